// Round 6
// baseline (458.445 us; speedup 1.0000x reference)
//
#include <hip/hip_runtime.h>

#define C_GMS 0.0026f

// DPP wavefront shifts: full-rate VALU cross-lane, zero LDS latency.
// dppL = value of lane-1 (wf_shr:1, 0x138), lane 0 reads 0 (bound_ctrl)
// dppR = value of lane+1 (wf_shl:1, 0x130), lane 63 reads 0
__device__ __forceinline__ float dppL(float x) {
    return __int_as_float(__builtin_amdgcn_mov_dpp(__float_as_int(x), 0x138, 0xf, 0xf, true));
}
__device__ __forceinline__ float dppR(float x) {
    return __int_as_float(__builtin_amdgcn_mov_dpp(__float_as_int(x), 0x130, 0xf, 0xf, true));
}
__device__ __forceinline__ float med3f(float a, float b, float c) {
    return __builtin_amdgcn_fmed3f(a, b, c);   // exact median-of-3, 1 instr
}

// Pooled-gray value at scale factor F: mean of an FxF RGB block over 3
// channels. (r,c) in scale coords, fully in-bounds. p = image base [3,512,512].
template<int F>
__device__ __forceinline__ float grayval(const float* __restrict__ p, int r, int c) {
    constexpr int HW = 512 * 512;
    float s = 0.0f;
    #pragma unroll 1                    // keep VGPR pressure low for F=4/8
    for (int fr = 0; fr < F; ++fr) {
        const float* row = p + (size_t)(r * F + fr) * 512 + c * F;
        #pragma unroll
        for (int ch = 0; ch < 3; ++ch) {
            const float* q = row + ch * HW;
            if constexpr (F == 1) {
                s += q[0];
            } else if constexpr (F == 2) {
                float2 t = *(const float2*)q; s += t.x + t.y;
            } else if constexpr (F == 4) {
                float4 t = *(const float4*)q; s += (t.x + t.y) + (t.z + t.w);
            } else {
                float4 t0 = *(const float4*)q;
                float4 t1 = *(const float4*)(q + 4);
                s += ((t0.x + t0.y) + (t0.z + t0.w)) + ((t1.x + t1.y) + (t1.z + t1.w));
            }
        }
    }
    return s * (1.0f / (3.0f * F * F));
}

// One wave owns a 64-col strip (60 output cols) at scale F, rolls down 8
// output rows. All state in registers; cross-column via DPP. No LDS tiles,
// no atomics in the hot path. median9 = med3(max3(lo), med3(me), min3(hi)).
// Rolling core verified exact in R3-R5 (absmax = 0).
template<int F>
__device__ __forceinline__ void gms_phase(
    int u, const float* __restrict__ Ii, const float* __restrict__ Ir,
    int nstrips, int nchunks, float* __restrict__ partial)
{
    constexpr int Hk = 512 / F;        // square: Wk == Hk
    constexpr int RC = 8;
    const int lane = threadIdx.x & 63;

    const int s  = u % nstrips;        // strip fastest: adjacent waves share halo in L2
    const int t1 = u / nstrips;
    const int k  = t1 % nchunks;
    const int b  = t1 / nchunks;

    const int c  = 60 * s - 1 + lane;  // my gray column (scale coords)
    const int R0 = k * RC;
    const int iend = min(R0 + RC, Hk - 2);

    const float* PX = Ii + (size_t)b * 3 * 512 * 512;
    const float* PY = Ir + (size_t)b * 3 * 512 * 512;
    const bool cok = (c >= 0) && (c < Hk);

    auto loadrow2 = [&](int r, float& vx, float& vy) {
        vx = 0.0f; vy = 0.0f;
        if (r >= 0 && r < Hk && cok) {          // zero-pad OOB (median pad)
            vx = grayval<F>(PX, r, c);
            vy = grayval<F>(PY, r, c);
        }
    };

    // column triple sort + DPP combine; rs = 3-wide horiz sum of medians (Gy)
    auto medrow = [&](float ga, float gb, float gc, float& m, float& rs) {
        float lo = fminf(fminf(ga, gb), gc);
        float me = med3f(ga, gb, gc);
        float hi = fmaxf(fmaxf(ga, gb), gc);
        float lmax = fmaxf(fmaxf(dppL(lo), lo), dppR(lo));
        float mid  = med3f(dppL(me), me, dppR(me));
        float hmin = fminf(fminf(dppL(hi), hi), dppR(hi));
        m  = med3f(lmax, mid, hmin);
        rs = m + dppL(m) + dppR(m);
    };

    // warmup: gray rows R0-1 .. R0+3 -> median rows R0..R0+2
    float xa, ya, xb, yb, xc, yc, xd, yd, xe, ye;
    loadrow2(R0 - 1, xa, ya);
    loadrow2(R0,     xb, yb);
    loadrow2(R0 + 1, xc, yc);
    loadrow2(R0 + 2, xd, yd);
    loadrow2(R0 + 3, xe, ye);

    float mx0, mx1, mx2, rx0, rx1, rx2;
    float my0, my1, my2, ry0, ry1, ry2;
    medrow(xa, xb, xc, mx0, rx0); medrow(ya, yb, yc, my0, ry0);
    medrow(xb, xc, xd, mx1, rx1); medrow(yb, yc, yd, my1, ry1);
    medrow(xc, xd, xe, mx2, rx2); medrow(yc, yd, ye, my2, ry2);

    float gx2 = xd, gx3 = xe, gy2 = yd, gy3 = ye;   // gray rows i+2, i+3

    const bool outLane = (lane >= 2) && (lane <= 61) && (c <= Hk - 2);
    float acc = 0.0f;

    for (int i = R0; i < iend; ++i) {
        float nx, ny;
        loadrow2(i + 4, nx, ny);               // prefetch next gray row

        // Prewitt + GMS for output row i (median rows i..i+2)
        float csx = mx0 + mx1 + mx2;
        float csy = my0 + my1 + my2;
        float Gxx = dppR(csx) - dppL(csx);
        float Gxy = dppR(csy) - dppL(csy);
        float Gyx = rx0 - rx2;
        float Gyy = ry0 - ry2;
        float gI = sqrtf(Gxx * Gxx + Gyx * Gyx) * (1.0f / 3.0f);
        float gR = sqrtf(Gxy * Gxy + Gyy * Gyy) * (1.0f / 3.0f);
        float gmap = (2.0f * gI * gR + C_GMS) / (gI * gI + gR * gR + C_GMS);
        if (outLane) acc += 1.0f - gmap;

        // median row i+3 from gray rows i+2..i+4
        float mxn, rxn, myn, ryn;
        medrow(gx2, gx3, nx, mxn, rxn);
        medrow(gy2, gy3, ny, myn, ryn);
        mx0 = mx1; mx1 = mx2; mx2 = mxn; rx0 = rx1; rx1 = rx2; rx2 = rxn;
        my0 = my1; my1 = my2; my2 = myn; ry0 = ry1; ry1 = ry2; ry2 = ryn;
        gx2 = gx3; gx3 = nx; gy2 = gy3; gy3 = ny;
    }

    for (int off = 32; off; off >>= 1) acc += __shfl_down(acc, off, 64);
    if (lane == 0)
        __hip_atomic_store(&partial[u], acc, __ATOMIC_RELAXED, __HIP_MEMORY_SCOPE_AGENT);
}

// unit layout: [0,9216) scale0 F=1 | [,11776) F=2 | [,12544) F=4 | [,12800) F=8
#define N0 9216
#define N1 2560
#define N2 768
#define N3 256
#define NTOT (N0 + N1 + N2 + N3)

__global__ __launch_bounds__(256) void msgms_main(
    const float* __restrict__ Ii, const float* __restrict__ Ir,
    float* __restrict__ P, unsigned int* __restrict__ counter,
    float* __restrict__ out)
{
    const int u = blockIdx.x * 4 + (threadIdx.x >> 6);
    if      (u < N0)                gms_phase<1>(u,                 Ii, Ir, 9, 64, P);
    else if (u < N0 + N1)           gms_phase<2>(u - N0,            Ii, Ir, 5, 32, P + N0);
    else if (u < N0 + N1 + N2)      gms_phase<4>(u - N0 - N1,       Ii, Ir, 3, 16, P + N0 + N1);
    else                            gms_phase<8>(u - N0 - N1 - N2,  Ii, Ir, 2,  8, P + N0 + N1 + N2);

    // ---- last-block finalize (no extra dispatch boundary) ----
    __shared__ int lastFlag;
    __syncthreads();
    if (threadIdx.x == 0) {
        __threadfence();   // release: make this block's partials visible device-wide
        unsigned int old = __hip_atomic_fetch_add(counter, 1u, __ATOMIC_ACQ_REL,
                                                  __HIP_MEMORY_SCOPE_AGENT);
        lastFlag = (old == (unsigned int)(gridDim.x - 1));
    }
    __syncthreads();
    if (!lastFlag) return;

    __threadfence();       // acquire side
    const int tid = threadIdx.x;
    const double w0 = 1.0 / (4.0 * 16.0 * 510.0 * 510.0);
    const double w1 = 1.0 / (4.0 * 16.0 * 254.0 * 254.0);
    const double w2 = 1.0 / (4.0 * 16.0 * 126.0 * 126.0);
    const double w3 = 1.0 / (4.0 * 16.0 * 62.0 * 62.0);
    double v = 0.0;
    for (int i = tid; i < NTOT; i += 256) {
        float p = __hip_atomic_load(&P[i], __ATOMIC_RELAXED, __HIP_MEMORY_SCOPE_AGENT);
        double w = (i < N0) ? w0 : (i < N0 + N1) ? w1 : (i < N0 + N1 + N2) ? w2 : w3;
        v += (double)p * w;
    }
    for (int off = 32; off; off >>= 1) v += __shfl_down(v, off, 64);
    __shared__ double wsum[4];
    if ((tid & 63) == 0) wsum[tid >> 6] = v;
    __syncthreads();
    if (tid == 0) out[0] = (float)(wsum[0] + wsum[1] + wsum[2] + wsum[3]);
}

extern "C" void kernel_launch(void* const* d_in, const int* in_sizes, int n_in,
                              void* d_out, int out_size, void* d_ws, size_t ws_size,
                              hipStream_t stream) {
    const float* Ii = (const float*)d_in[0];
    const float* Ir = (const float*)d_in[1];
    float* out = (float*)d_out;

    char* ws = (char*)d_ws;
    unsigned int* counter = (unsigned int*)ws;      // 4 B used, 256 B reserved
    float* P = (float*)(ws + 256);                  // NTOT partials

    hipMemsetAsync(counter, 0, 256, stream);        // trivial leading node

    msgms_main<<<NTOT / 4, 256, 0, stream>>>(Ii, Ir, P, counter, out);
}